// Round 1
// baseline (234.711 us; speedup 1.0000x reference)
//
#include <hip/hip_runtime.h>

#define HEADS 16
#define HDIM 64
#define EMB 1024
#define SEQ 2048
#define NBATCH 2

typedef short short8 __attribute__((ext_vector_type(8)));
typedef float f32x4 __attribute__((ext_vector_type(4)));

__device__ __forceinline__ unsigned short f2bf(float f) {
  unsigned u = __builtin_bit_cast(unsigned, f);
  u += 0x7fffu + ((u >> 16) & 1u);
  return (unsigned short)(u >> 16);
}

// ---------------------------------------------------------------------------
// Wo fp32 -> bf16
// ---------------------------------------------------------------------------
__global__ __launch_bounds__(256) void convbf_kernel(const float* __restrict__ src,
                                                     unsigned short* __restrict__ dst) {
  int i = (blockIdx.x * 256 + threadIdx.x) * 4;
  float4 v = *(const float4*)(src + i);
  unsigned short a = f2bf(v.x), b = f2bf(v.y), c = f2bf(v.z), d = f2bf(v.w);
  uint2 pk;
  pk.x = (unsigned)a | ((unsigned)b << 16);
  pk.y = (unsigned)c | ((unsigned)d << 16);
  *(uint2*)(dst + i) = pk;
}

// ---------------------------------------------------------------------------
// Per-head projections. tensor 0=q (scaled, normal layout), 1=k (normal),
// 2=v (transposed [n][h][d][l]).
// x layout: [n][l][h*64+d] fp32. W: [64][64] fp32, y = x @ W^T.
// ---------------------------------------------------------------------------
__global__ __launch_bounds__(256) void proj_kernel(
    const float* __restrict__ q_in, const float* __restrict__ k_in,
    const float* __restrict__ v_in, const float* __restrict__ Wq,
    const float* __restrict__ Wk, const float* __restrict__ Wv,
    unsigned short* __restrict__ qp, unsigned short* __restrict__ kp,
    unsigned short* __restrict__ vt, float qscale) {
  int t = threadIdx.x;
  int lb = blockIdx.x;      // L/256
  int h = blockIdx.y;       // head
  int zz = blockIdx.z;      // tensor*2 + n
  int tensor = zz >> 1, n = zz & 1;

  const float* x;
  const float* W;
  float scale = 1.0f;
  if (tensor == 0) { x = q_in; W = Wq; scale = qscale; }
  else if (tensor == 1) { x = k_in; W = Wk; }
  else { x = v_in; W = Wv; }

  __shared__ float Wl[64 * 64];
#pragma unroll
  for (int i = 0; i < 16; ++i) Wl[t + i * 256] = W[t + i * 256];
  __syncthreads();

  int l = lb * 256 + t;
  const float* xr = x + ((size_t)(n * SEQ + l) * HEADS + h) * HDIM;
  float xv[64];
#pragma unroll
  for (int i = 0; i < 16; ++i) {
    float4 v4 = *(const float4*)(xr + i * 4);
    xv[i * 4 + 0] = v4.x; xv[i * 4 + 1] = v4.y;
    xv[i * 4 + 2] = v4.z; xv[i * 4 + 3] = v4.w;
  }

  size_t slab = (size_t)(n * HEADS + h);
  if (tensor < 2) {
    unsigned short* outp = (tensor == 0 ? qp : kp) + (slab * SEQ + l) * HDIM;
    for (int e8 = 0; e8 < 8; ++e8) {
      float ye[8];
#pragma unroll
      for (int ei = 0; ei < 8; ++ei) {
        const float* wr = &Wl[(e8 * 8 + ei) * 64];
        float acc = 0.0f;
#pragma unroll
        for (int d4 = 0; d4 < 16; ++d4) {
          float4 w4 = *(const float4*)(wr + d4 * 4);
          acc += xv[d4 * 4 + 0] * w4.x + xv[d4 * 4 + 1] * w4.y +
                 xv[d4 * 4 + 2] * w4.z + xv[d4 * 4 + 3] * w4.w;
        }
        ye[ei] = acc * scale;
      }
      uint4 pk;
      pk.x = (unsigned)f2bf(ye[0]) | ((unsigned)f2bf(ye[1]) << 16);
      pk.y = (unsigned)f2bf(ye[2]) | ((unsigned)f2bf(ye[3]) << 16);
      pk.z = (unsigned)f2bf(ye[4]) | ((unsigned)f2bf(ye[5]) << 16);
      pk.w = (unsigned)f2bf(ye[6]) | ((unsigned)f2bf(ye[7]) << 16);
      *(uint4*)(outp + e8 * 8) = pk;
    }
  } else {
    unsigned short* outp = vt + slab * HDIM * SEQ + l;
    for (int e = 0; e < 64; ++e) {
      const float* wr = &Wl[e * 64];
      float acc = 0.0f;
#pragma unroll
      for (int d4 = 0; d4 < 16; ++d4) {
        float4 w4 = *(const float4*)(wr + d4 * 4);
        acc += xv[d4 * 4 + 0] * w4.x + xv[d4 * 4 + 1] * w4.y +
               xv[d4 * 4 + 2] * w4.z + xv[d4 * 4 + 3] * w4.w;
      }
      outp[(size_t)e * SEQ] = f2bf(acc);
    }
  }
}

// ---------------------------------------------------------------------------
// Flash attention. qp/kp: [n][h][l][d] bf16 (q pre-scaled by log2e/32),
// vt: [n][h][d][l] bf16. Output ao: [n][l][h*64+d] bf16.
// Block: 256 thr (4 waves), QBLK=64 (16 rows/wave), KBLK=64.
// ---------------------------------------------------------------------------
__global__ __launch_bounds__(256) void attn_kernel(
    const unsigned short* __restrict__ qp, const unsigned short* __restrict__ kp,
    const unsigned short* __restrict__ vt, const int* __restrict__ mask,
    unsigned short* __restrict__ ao) {
  int t = threadIdx.x;
  int w = t >> 6;
  int lane = t & 63;
  int lr = lane & 15, lg = lane >> 4;
  int qb = blockIdx.x * 64;
  int h = blockIdx.y, n = blockIdx.z;
  size_t slab = (size_t)(n * HEADS + h);
  const unsigned short* Qb = qp + slab * SEQ * HDIM;
  const unsigned short* Kb = kp + slab * SEQ * HDIM;
  const unsigned short* Vb = vt + slab * (size_t)HDIM * SEQ;

  __shared__ uint4 Kl[512];       // [64 rows][8 x 16B], XOR-swizzled
  __shared__ uint4 Vl[512];       // [d 0..63][l 0..63], XOR-swizzled
  __shared__ uint4 Pl[4 * 128];   // per-wave P tile [16][64] bf16, swizzled
  __shared__ float biasl[64];

  // Q A-fragments (held for the whole loop)
  short8 aq0, aq1;
  {
    const unsigned short* qrow = Qb + (size_t)(qb + w * 16 + lr) * HDIM + lg * 8;
    aq0 = __builtin_bit_cast(short8, *(const uint4*)(qrow));
    aq1 = __builtin_bit_cast(short8, *(const uint4*)(qrow + 32));
  }

  f32x4 zero = {0.0f, 0.0f, 0.0f, 0.0f};
  f32x4 acc[4];
  float mrun[4], lrun[4];
#pragma unroll
  for (int i = 0; i < 4; ++i) { acc[i] = zero; mrun[i] = -1e30f; lrun[i] = 0.0f; }

  for (int kb = 0; kb < SEQ; kb += 64) {
    __syncthreads();
    // ---- stage K and V tiles (reg-staged, swizzled) ----
#pragma unroll
    for (int s = 0; s < 2; ++s) {
      int c = t + s * 256;
      int row = c >> 3, c16 = c & 7;
      uint4 kv = *(const uint4*)(Kb + (size_t)(kb + row) * HDIM + c16 * 8);
      uint4 vv = *(const uint4*)(Vb + (size_t)row * SEQ + kb + c16 * 8);
      int idx = (row * 8 + c16) ^ (row & 7);
      Kl[idx] = kv;
      Vl[idx] = vv;
    }
    if (t < 64) biasl[t] = mask[n * SEQ + kb + t] ? 0.0f : -1e30f;
    __syncthreads();

    // ---- QK^T (S in log2 domain; q pre-scaled) ----
    f32x4 s[4];
#pragma unroll
    for (int nt = 0; nt < 4; ++nt) {
      int row = nt * 16 + lr;
      short8 bk0 = __builtin_bit_cast(short8, Kl[(row * 8 + lg) ^ (row & 7)]);
      short8 bk1 = __builtin_bit_cast(short8, Kl[(row * 8 + 4 + lg) ^ (row & 7)]);
      f32x4 z = zero;
      z = __builtin_amdgcn_mfma_f32_16x16x32_bf16(aq0, bk0, z, 0, 0, 0);
      z = __builtin_amdgcn_mfma_f32_16x16x32_bf16(aq1, bk1, z, 0, 0, 0);
      s[nt] = z;
    }
#pragma unroll
    for (int nt = 0; nt < 4; ++nt) {
      float bv = biasl[nt * 16 + lr];
#pragma unroll
      for (int i = 0; i < 4; ++i) s[nt][i] += bv;
    }

    // ---- online softmax (rows live in reg i, cols across lanes 0..15) ----
    float rm[4];
#pragma unroll
    for (int i = 0; i < 4; ++i)
      rm[i] = fmaxf(fmaxf(s[0][i], s[1][i]), fmaxf(s[2][i], s[3][i]));
#pragma unroll
    for (int m = 1; m < 16; m <<= 1) {
#pragma unroll
      for (int i = 0; i < 4; ++i) rm[i] = fmaxf(rm[i], __shfl_xor(rm[i], m, 64));
    }
    float rs[4];
#pragma unroll
    for (int i = 0; i < 4; ++i) {
      float mn = fmaxf(mrun[i], rm[i]);
      rs[i] = exp2f(mrun[i] - mn);
      mrun[i] = mn;
    }
    float ps[4] = {0.0f, 0.0f, 0.0f, 0.0f};
    unsigned short* Pw = (unsigned short*)&Pl[w * 128];
#pragma unroll
    for (int nt = 0; nt < 4; ++nt) {
#pragma unroll
      for (int i = 0; i < 4; ++i) {
        float p = exp2f(s[nt][i] - mrun[i]);
        ps[i] += p;
        int r = lg * 4 + i;
        Pw[(r * 64 + nt * 16 + lr) ^ ((r & 7) << 3)] = f2bf(p);
      }
    }
#pragma unroll
    for (int m = 1; m < 16; m <<= 1) {
#pragma unroll
      for (int i = 0; i < 4; ++i) ps[i] += __shfl_xor(ps[i], m, 64);
    }
#pragma unroll
    for (int i = 0; i < 4; ++i) lrun[i] = lrun[i] * rs[i] + ps[i];
#pragma unroll
    for (int nt = 0; nt < 4; ++nt)
#pragma unroll
      for (int i = 0; i < 4; ++i) acc[nt][i] *= rs[i];

    // ---- P @ V ----
    asm volatile("s_waitcnt lgkmcnt(0)" ::: "memory");
    short8 pa0 = __builtin_bit_cast(short8, Pl[w * 128 + ((lr * 8 + lg) ^ (lr & 7))]);
    short8 pa1 = __builtin_bit_cast(short8, Pl[w * 128 + ((lr * 8 + 4 + lg) ^ (lr & 7))]);
#pragma unroll
    for (int nt = 0; nt < 4; ++nt) {
      int row = nt * 16 + lr;
      short8 bv0 = __builtin_bit_cast(short8, Vl[(row * 8 + lg) ^ (row & 7)]);
      short8 bv1 = __builtin_bit_cast(short8, Vl[(row * 8 + 4 + lg) ^ (row & 7)]);
      acc[nt] = __builtin_amdgcn_mfma_f32_16x16x32_bf16(pa0, bv0, acc[nt], 0, 0, 0);
      acc[nt] = __builtin_amdgcn_mfma_f32_16x16x32_bf16(pa1, bv1, acc[nt], 0, 0, 0);
    }
  }

  // ---- epilogue: normalize, write [n][l][e] bf16 ----
#pragma unroll
  for (int nt = 0; nt < 4; ++nt) {
#pragma unroll
    for (int i = 0; i < 4; ++i) {
      float o = acc[nt][i] / lrun[i];
      int qrow = qb + w * 16 + lg * 4 + i;
      ao[((size_t)(n * SEQ + qrow)) * EMB + h * HDIM + nt * 16 + lr] = f2bf(o);
    }
  }
}

// ---------------------------------------------------------------------------
// Out-projection: C[M=4096][N=1024] = A[M][K=1024] @ B[N][K]^T + bias
// A = attention out bf16, B = Wo bf16. 128x64 tile, BK=64.
// ---------------------------------------------------------------------------
__global__ __launch_bounds__(256) void gemm_bt_kernel(
    const unsigned short* __restrict__ A, const unsigned short* __restrict__ B,
    const float* __restrict__ bias, float* __restrict__ Cm) {
  int t = threadIdx.x;
  int lane = t & 63, w = t >> 6;
  int lr = lane & 15, lg = lane >> 4;
  int m0 = blockIdx.y * 128, n0 = blockIdx.x * 64;
  int wr = w >> 1, wc = w & 1;  // wave tile 64x32

  __shared__ uint4 Al[1024];  // 128 rows x 8 chunks
  __shared__ uint4 Bl[512];   // 64 rows x 8 chunks

  f32x4 zero = {0.0f, 0.0f, 0.0f, 0.0f};
  f32x4 acc[4][2];
#pragma unroll
  for (int mt = 0; mt < 4; ++mt)
#pragma unroll
    for (int nt = 0; nt < 2; ++nt) acc[mt][nt] = zero;

  for (int kt = 0; kt < EMB; kt += 64) {
    __syncthreads();
#pragma unroll
    for (int s = 0; s < 4; ++s) {
      int c = t + s * 256;
      int row = c >> 3, c16 = c & 7;
      uint4 v = *(const uint4*)(A + (size_t)(m0 + row) * EMB + kt + c16 * 8);
      Al[(row * 8 + c16) ^ (row & 7)] = v;
    }
#pragma unroll
    for (int s = 0; s < 2; ++s) {
      int c = t + s * 256;
      int row = c >> 3, c16 = c & 7;
      uint4 v = *(const uint4*)(B + (size_t)(n0 + row) * EMB + kt + c16 * 8);
      Bl[(row * 8 + c16) ^ (row & 7)] = v;
    }
    __syncthreads();
#pragma unroll
    for (int kk = 0; kk < 2; ++kk) {
      short8 af[4], bfr[2];
#pragma unroll
      for (int mt = 0; mt < 4; ++mt) {
        int row = wr * 64 + mt * 16 + lr;
        af[mt] = __builtin_bit_cast(short8, Al[(row * 8 + kk * 4 + lg) ^ (row & 7)]);
      }
#pragma unroll
      for (int nt = 0; nt < 2; ++nt) {
        int row = wc * 32 + nt * 16 + lr;
        bfr[nt] = __builtin_bit_cast(short8, Bl[(row * 8 + kk * 4 + lg) ^ (row & 7)]);
      }
#pragma unroll
      for (int mt = 0; mt < 4; ++mt)
#pragma unroll
        for (int nt = 0; nt < 2; ++nt)
          acc[mt][nt] = __builtin_amdgcn_mfma_f32_16x16x32_bf16(af[mt], bfr[nt],
                                                                acc[mt][nt], 0, 0, 0);
    }
  }

#pragma unroll
  for (int nt = 0; nt < 2; ++nt) {
    int col = n0 + wc * 32 + nt * 16 + lr;
    float bv = bias[col];
#pragma unroll
    for (int mt = 0; mt < 4; ++mt) {
#pragma unroll
      for (int i = 0; i < 4; ++i) {
        int rowm = m0 + wr * 64 + mt * 16 + lg * 4 + i;
        Cm[(size_t)rowm * EMB + col] = acc[mt][nt][i] + bv;
      }
    }
  }
}

// ---------------------------------------------------------------------------
extern "C" void kernel_launch(void* const* d_in, const int* in_sizes, int n_in,
                              void* d_out, int out_size, void* d_ws, size_t ws_size,
                              hipStream_t stream) {
  const float* values = (const float*)d_in[0];
  const float* keys   = (const float*)d_in[1];
  const float* query  = (const float*)d_in[2];
  const int*   mask   = (const int*)d_in[3];
  const float* Wv     = (const float*)d_in[4];
  const float* Wk     = (const float*)d_in[5];
  const float* Wq     = (const float*)d_in[6];
  const float* Wo     = (const float*)d_in[7];
  const float* bo     = (const float*)d_in[8];
  float* out = (float*)d_out;

  const size_t slab = (size_t)NBATCH * HEADS * SEQ * HDIM;  // 4,194,304 elems
  unsigned short* qp  = (unsigned short*)d_ws;
  unsigned short* kp  = qp + slab;
  unsigned short* vt  = kp + slab;
  unsigned short* ao  = vt + slab;
  unsigned short* wob = ao + slab;

  // scale: 1/sqrt(EMB) folded with log2(e) so softmax = exp2
  float qscale = 1.4426950408889634f / 32.0f;

  convbf_kernel<<<dim3(EMB * EMB / 1024), 256, 0, stream>>>(Wo, wob);
  proj_kernel<<<dim3(SEQ / 256, HEADS, 6), 256, 0, stream>>>(
      query, keys, values, Wq, Wk, Wv, qp, kp, vt, qscale);
  attn_kernel<<<dim3(SEQ / 64, HEADS, NBATCH), 256, 0, stream>>>(qp, kp, vt, mask, ao);
  gemm_bt_kernel<<<dim3(EMB / 64, (NBATCH * SEQ) / 128), 256, 0, stream>>>(ao, wob, bo, out);
}

// Round 2
// 189.420 us; speedup vs baseline: 1.2391x; 1.2391x over previous
//
#include <hip/hip_runtime.h>

#define HEADS 16
#define HDIM 64
#define EMB 1024
#define SEQ 2048
#define NBATCH 2

typedef short short8 __attribute__((ext_vector_type(8)));
typedef float f32x4 __attribute__((ext_vector_type(4)));

__device__ __forceinline__ unsigned short f2bf(float f) {
  unsigned u = __builtin_bit_cast(unsigned, f);
  u += 0x7fffu + ((u >> 16) & 1u);
  return (unsigned short)(u >> 16);
}

__device__ __forceinline__ unsigned cvtpk(float lo, float hi) {
  unsigned r;
  asm("v_cvt_pk_bf16_f32 %0, %1, %2" : "=v"(r) : "v"(lo), "v"(hi));
  return r;
}

// ---------------------------------------------------------------------------
// prep: Wo fp32->bf16 (blocks 0..1023) + mask -> float bias (blocks 1024..1027)
// ---------------------------------------------------------------------------
__global__ __launch_bounds__(256) void prep_kernel(const float* __restrict__ src,
                                                   unsigned short* __restrict__ dst,
                                                   const int* __restrict__ mask,
                                                   float* __restrict__ biasf) {
  int b = blockIdx.x;
  if (b < 1024) {
    int i = (b * 256 + threadIdx.x) * 4;
    float4 v = *(const float4*)(src + i);
    uint2 pk;
    pk.x = (unsigned)f2bf(v.x) | ((unsigned)f2bf(v.y) << 16);
    pk.y = (unsigned)f2bf(v.z) | ((unsigned)f2bf(v.w) << 16);
    *(uint2*)(dst + i) = pk;
  } else {
    int i = (b - 1024) * 1024 + threadIdx.x * 4;
    int4 m = *(const int4*)(mask + i);
    float4 o;
    o.x = m.x ? 0.0f : -1e30f;
    o.y = m.y ? 0.0f : -1e30f;
    o.z = m.z ? 0.0f : -1e30f;
    o.w = m.w ? 0.0f : -1e30f;
    *(float4*)(biasf + i) = o;
  }
}

// ---------------------------------------------------------------------------
// Per-head projections (unchanged from round 1, verified).
// tensor 0=q (scaled), 1=k, 2=v (transposed [n][h][d][l]).
// ---------------------------------------------------------------------------
__global__ __launch_bounds__(256) void proj_kernel(
    const float* __restrict__ q_in, const float* __restrict__ k_in,
    const float* __restrict__ v_in, const float* __restrict__ Wq,
    const float* __restrict__ Wk, const float* __restrict__ Wv,
    unsigned short* __restrict__ qp, unsigned short* __restrict__ kp,
    unsigned short* __restrict__ vt, float qscale) {
  int t = threadIdx.x;
  int lb = blockIdx.x;
  int h = blockIdx.y;
  int zz = blockIdx.z;
  int tensor = zz >> 1, n = zz & 1;

  const float* x;
  const float* W;
  float scale = 1.0f;
  if (tensor == 0) { x = q_in; W = Wq; scale = qscale; }
  else if (tensor == 1) { x = k_in; W = Wk; }
  else { x = v_in; W = Wv; }

  __shared__ float Wl[64 * 64];
#pragma unroll
  for (int i = 0; i < 16; ++i) Wl[t + i * 256] = W[t + i * 256];
  __syncthreads();

  int l = lb * 256 + t;
  const float* xr = x + ((size_t)(n * SEQ + l) * HEADS + h) * HDIM;
  float xv[64];
#pragma unroll
  for (int i = 0; i < 16; ++i) {
    float4 v4 = *(const float4*)(xr + i * 4);
    xv[i * 4 + 0] = v4.x; xv[i * 4 + 1] = v4.y;
    xv[i * 4 + 2] = v4.z; xv[i * 4 + 3] = v4.w;
  }

  size_t slab = (size_t)(n * HEADS + h);
  if (tensor < 2) {
    unsigned short* outp = (tensor == 0 ? qp : kp) + (slab * SEQ + l) * HDIM;
    for (int e8 = 0; e8 < 8; ++e8) {
      float ye[8];
#pragma unroll
      for (int ei = 0; ei < 8; ++ei) {
        const float* wr = &Wl[(e8 * 8 + ei) * 64];
        float acc = 0.0f;
#pragma unroll
        for (int d4 = 0; d4 < 16; ++d4) {
          float4 w4 = *(const float4*)(wr + d4 * 4);
          acc += xv[d4 * 4 + 0] * w4.x + xv[d4 * 4 + 1] * w4.y +
                 xv[d4 * 4 + 2] * w4.z + xv[d4 * 4 + 3] * w4.w;
        }
        ye[ei] = acc * scale;
      }
      uint4 pk;
      pk.x = (unsigned)f2bf(ye[0]) | ((unsigned)f2bf(ye[1]) << 16);
      pk.y = (unsigned)f2bf(ye[2]) | ((unsigned)f2bf(ye[3]) << 16);
      pk.z = (unsigned)f2bf(ye[4]) | ((unsigned)f2bf(ye[5]) << 16);
      pk.w = (unsigned)f2bf(ye[6]) | ((unsigned)f2bf(ye[7]) << 16);
      *(uint4*)(outp + e8 * 8) = pk;
    }
  } else {
    unsigned short* outp = vt + slab * HDIM * SEQ + l;
    for (int e = 0; e < 64; ++e) {
      const float* wr = &Wl[e * 64];
      float acc = 0.0f;
#pragma unroll
      for (int d4 = 0; d4 < 16; ++d4) {
        float4 w4 = *(const float4*)(wr + d4 * 4);
        acc += xv[d4 * 4 + 0] * w4.x + xv[d4 * 4 + 1] * w4.y +
               xv[d4 * 4 + 2] * w4.z + xv[d4 * 4 + 3] * w4.w;
      }
      outp[(size_t)e * SEQ] = f2bf(acc);
    }
  }
}

// ---------------------------------------------------------------------------
// Flash attention v2: swapped QK^T, in-register softmax.
// qp/kp: [n][h][l][d] bf16 (q pre-scaled by log2e/32), vt: [n][h][d][l] bf16.
// biasf: [n][k] fp32 (0 or -1e30). Output ao: [n][l][h*64+d] bf16.
// Block 256 = 4 waves; wave owns 16 q-rows (q = qb + w*16 + lane&15).
// ---------------------------------------------------------------------------
__global__ __launch_bounds__(256) void attn_kernel(
    const unsigned short* __restrict__ qp, const unsigned short* __restrict__ kp,
    const unsigned short* __restrict__ vt, const float* __restrict__ biasf,
    unsigned short* __restrict__ ao) {
  int t = threadIdx.x;
  int w = t >> 6;
  int lane = t & 63;
  int lr = lane & 15, lg = lane >> 4;
  int qb = blockIdx.x * 64;
  int h = blockIdx.y, n = blockIdx.z;
  size_t slab = (size_t)(n * HEADS + h);
  const unsigned short* Qb = qp + slab * SEQ * HDIM;
  const unsigned short* Kb = kp + slab * SEQ * HDIM;
  const unsigned short* Vb = vt + slab * (size_t)HDIM * SEQ;
  const float* biasp = biasf + n * SEQ;

  __shared__ uint4 Kl[512];      // [64 k-rows][8 x 16B], XOR-swizzled
  __shared__ uint4 Vl[512];      // [64 d-rows][8 x 16B], XOR-swizzled
  __shared__ unsigned Pl[4 * 512];  // per-wave P^T->B-frag tile [16 q][32 words]

  // Q B-fragments, held all loop: lane holds Q[q=qb+w*16+lr][d=lg*8..]
  short8 bq0, bq1;
  {
    const unsigned short* qrow = Qb + (size_t)(qb + w * 16 + lr) * HDIM + lg * 8;
    bq0 = __builtin_bit_cast(short8, *(const uint4*)(qrow));
    bq1 = __builtin_bit_cast(short8, *(const uint4*)(qrow + 32));
  }

  f32x4 zero = {0.0f, 0.0f, 0.0f, 0.0f};
  f32x4 acc[4];
#pragma unroll
  for (int i = 0; i < 4; ++i) acc[i] = zero;
  float mrun = -1e30f, lrun = 0.0f;

  unsigned* Pw = Pl + w * 512 + lr * 32;
  const int swz = (lr & 7) << 2;

  for (int kb = 0; kb < SEQ; kb += 64) {
    __syncthreads();
    // ---- stage K and V tiles ----
#pragma unroll
    for (int s = 0; s < 2; ++s) {
      int c = t + s * 256;
      int row = c >> 3, c16 = c & 7;
      uint4 kv = *(const uint4*)(Kb + (size_t)(kb + row) * HDIM + c16 * 8);
      uint4 vv = *(const uint4*)(Vb + (size_t)row * SEQ + kb + c16 * 8);
      int idx = (row * 8 + c16) ^ (row & 7);
      Kl[idx] = kv;
      Vl[idx] = vv;
    }
    __syncthreads();

    // ---- QK^T swapped: S^T[k][q]; lane holds 16 k-scores of q-row lr ----
    f32x4 s4[4];
#pragma unroll
    for (int nt = 0; nt < 4; ++nt) {
      int row = nt * 16 + lr;
      short8 a0 = __builtin_bit_cast(short8, Kl[(row * 8 + lg) ^ (row & 7)]);
      short8 a1 = __builtin_bit_cast(short8, Kl[(row * 8 + 4 + lg) ^ (row & 7)]);
      f32x4 z = __builtin_amdgcn_mfma_f32_16x16x32_bf16(a0, bq0, zero, 0, 0, 0);
      z = __builtin_amdgcn_mfma_f32_16x16x32_bf16(a1, bq1, z, 0, 0, 0);
      f32x4 bv = *(const f32x4*)(biasp + kb + nt * 16 + lg * 4);
      s4[nt] = z + bv;
    }

    // ---- row max: in-lane tree + 2 shuffles ----
    float rm;
    {
      f32x4 m01, m;
#pragma unroll
      for (int i = 0; i < 4; ++i)
        m01[i] = fmaxf(fmaxf(s4[0][i], s4[1][i]), fmaxf(s4[2][i], s4[3][i]));
      rm = fmaxf(fmaxf(m01[0], m01[1]), fmaxf(m01[2], m01[3]));
    }
    rm = fmaxf(rm, __shfl_xor(rm, 16, 64));
    rm = fmaxf(rm, __shfl_xor(rm, 32, 64));

    if (__any(rm > mrun)) {
      float mnew = fmaxf(mrun, rm);
      float rs = exp2f(mrun - mnew);
      mrun = mnew;
      lrun *= rs;
#pragma unroll
      for (int db = 0; db < 4; ++db) acc[db] = acc[db] * rs;
    }

    // ---- P = exp2(S - m), pack bf16 pairs, partial sum ----
    float ps = 0.0f;
    unsigned pk[8];
#pragma unroll
    for (int nt = 0; nt < 4; ++nt) {
      float p0 = exp2f(s4[nt][0] - mrun);
      float p1 = exp2f(s4[nt][1] - mrun);
      float p2 = exp2f(s4[nt][2] - mrun);
      float p3 = exp2f(s4[nt][3] - mrun);
      ps += (p0 + p1) + (p2 + p3);
      pk[nt * 2] = cvtpk(p0, p1);
      pk[nt * 2 + 1] = cvtpk(p2, p3);
    }
    ps += __shfl_xor(ps, 16, 64);
    ps += __shfl_xor(ps, 32, 64);
    lrun += ps;

    // ---- P^T -> B-frag layout via per-wave LDS (swizzled round-trip) ----
#pragma unroll
    for (int nt = 0; nt < 4; ++nt) {
      Pw[(nt * 8 + lg * 2) ^ swz] = pk[nt * 2];
      Pw[(nt * 8 + lg * 2 + 1) ^ swz] = pk[nt * 2 + 1];
    }
    asm volatile("s_waitcnt lgkmcnt(0)" ::: "memory");
    __builtin_amdgcn_sched_barrier(0);
    short8 pf0 = __builtin_bit_cast(short8, *(const uint4*)(Pw + ((lg * 4) ^ swz)));
    short8 pf1 = __builtin_bit_cast(short8, *(const uint4*)(Pw + ((16 + lg * 4) ^ swz)));

    // ---- PV: O^T[d][q] += V^T-frag x P-frag ----
#pragma unroll
    for (int db = 0; db < 4; ++db) {
      int row = db * 16 + lr;
      short8 v0 = __builtin_bit_cast(short8, Vl[(row * 8 + lg) ^ (row & 7)]);
      short8 v1 = __builtin_bit_cast(short8, Vl[(row * 8 + 4 + lg) ^ (row & 7)]);
      acc[db] = __builtin_amdgcn_mfma_f32_16x16x32_bf16(v0, pf0, acc[db], 0, 0, 0);
      acc[db] = __builtin_amdgcn_mfma_f32_16x16x32_bf16(v1, pf1, acc[db], 0, 0, 0);
    }
  }

  // ---- epilogue: lane holds O[q = qb+w*16+lr][d = db*16+lg*4+i] ----
  float inv = 1.0f / lrun;
  size_t obase = ((size_t)(n * SEQ + qb + w * 16 + lr)) * EMB + h * HDIM;
#pragma unroll
  for (int db = 0; db < 4; ++db) {
    uint2 o;
    o.x = cvtpk(acc[db][0] * inv, acc[db][1] * inv);
    o.y = cvtpk(acc[db][2] * inv, acc[db][3] * inv);
    *(uint2*)(ao + obase + db * 16 + lg * 4) = o;
  }
}

// ---------------------------------------------------------------------------
// Out-projection (unchanged from round 1, verified).
// ---------------------------------------------------------------------------
__global__ __launch_bounds__(256) void gemm_bt_kernel(
    const unsigned short* __restrict__ A, const unsigned short* __restrict__ B,
    const float* __restrict__ bias, float* __restrict__ Cm) {
  int t = threadIdx.x;
  int lane = t & 63, w = t >> 6;
  int lr = lane & 15, lg = lane >> 4;
  int m0 = blockIdx.y * 128, n0 = blockIdx.x * 64;
  int wr = w >> 1, wc = w & 1;

  __shared__ uint4 Al[1024];
  __shared__ uint4 Bl[512];

  f32x4 zero = {0.0f, 0.0f, 0.0f, 0.0f};
  f32x4 acc[4][2];
#pragma unroll
  for (int mt = 0; mt < 4; ++mt)
#pragma unroll
    for (int nt = 0; nt < 2; ++nt) acc[mt][nt] = zero;

  for (int kt = 0; kt < EMB; kt += 64) {
    __syncthreads();
#pragma unroll
    for (int s = 0; s < 4; ++s) {
      int c = t + s * 256;
      int row = c >> 3, c16 = c & 7;
      uint4 v = *(const uint4*)(A + (size_t)(m0 + row) * EMB + kt + c16 * 8);
      Al[(row * 8 + c16) ^ (row & 7)] = v;
    }
#pragma unroll
    for (int s = 0; s < 2; ++s) {
      int c = t + s * 256;
      int row = c >> 3, c16 = c & 7;
      uint4 v = *(const uint4*)(B + (size_t)(n0 + row) * EMB + kt + c16 * 8);
      Bl[(row * 8 + c16) ^ (row & 7)] = v;
    }
    __syncthreads();
#pragma unroll
    for (int kk = 0; kk < 2; ++kk) {
      short8 af[4], bfr[2];
#pragma unroll
      for (int mt = 0; mt < 4; ++mt) {
        int row = wr * 64 + mt * 16 + lr;
        af[mt] = __builtin_bit_cast(short8, Al[(row * 8 + kk * 4 + lg) ^ (row & 7)]);
      }
#pragma unroll
      for (int nt = 0; nt < 2; ++nt) {
        int row = wc * 32 + nt * 16 + lr;
        bfr[nt] = __builtin_bit_cast(short8, Bl[(row * 8 + kk * 4 + lg) ^ (row & 7)]);
      }
#pragma unroll
      for (int mt = 0; mt < 4; ++mt)
#pragma unroll
        for (int nt = 0; nt < 2; ++nt)
          acc[mt][nt] = __builtin_amdgcn_mfma_f32_16x16x32_bf16(af[mt], bfr[nt],
                                                                acc[mt][nt], 0, 0, 0);
    }
  }

#pragma unroll
  for (int nt = 0; nt < 2; ++nt) {
    int col = n0 + wc * 32 + nt * 16 + lr;
    float bv = bias[col];
#pragma unroll
    for (int mt = 0; mt < 4; ++mt) {
#pragma unroll
      for (int i = 0; i < 4; ++i) {
        int rowm = m0 + wr * 64 + mt * 16 + lg * 4 + i;
        Cm[(size_t)rowm * EMB + col] = acc[mt][nt][i] + bv;
      }
    }
  }
}

// ---------------------------------------------------------------------------
extern "C" void kernel_launch(void* const* d_in, const int* in_sizes, int n_in,
                              void* d_out, int out_size, void* d_ws, size_t ws_size,
                              hipStream_t stream) {
  const float* values = (const float*)d_in[0];
  const float* keys   = (const float*)d_in[1];
  const float* query  = (const float*)d_in[2];
  const int*   mask   = (const int*)d_in[3];
  const float* Wv     = (const float*)d_in[4];
  const float* Wk     = (const float*)d_in[5];
  const float* Wq     = (const float*)d_in[6];
  const float* Wo     = (const float*)d_in[7];
  const float* bo     = (const float*)d_in[8];
  float* out = (float*)d_out;

  const size_t slab = (size_t)NBATCH * HEADS * SEQ * HDIM;  // 4,194,304 elems
  unsigned short* qp  = (unsigned short*)d_ws;
  unsigned short* kp  = qp + slab;
  unsigned short* vt  = kp + slab;
  unsigned short* ao  = vt + slab;
  unsigned short* wob = ao + slab;
  float* biasf = (float*)(wob + (size_t)EMB * EMB);

  float qscale = 1.4426950408889634f / 32.0f;

  prep_kernel<<<dim3(1028), 256, 0, stream>>>(Wo, wob, mask, biasf);
  proj_kernel<<<dim3(SEQ / 256, HEADS, 6), 256, 0, stream>>>(
      query, keys, values, Wq, Wk, Wv, qp, kp, vt, qscale);
  attn_kernel<<<dim3(SEQ / 64, HEADS, NBATCH), 256, 0, stream>>>(qp, kp, vt, biasf, ao);
  gemm_bt_kernel<<<dim3(EMB / 64, (NBATCH * SEQ) / 128), 256, 0, stream>>>(ao, wob, bo, out);
}